// Round 9
// baseline (22.689 us; speedup 1.0000x reference)
//
#include <hip/hip_runtime.h>
#include <math.h>

#define NF   32
#define HGT  512
#define WID  512
#define BAT  8
#define HW   (HGT*WID)        // 262144
#define NPIX (BAT*HW)         // 2097152
#define NROWS (2*NPIX)        // 4194304
#define TPB  256

#define RROWS 2               // rows per wave strip
#define NBLKF 512             // 512 blocks x 4 waves = 2048 strips -> 2 waves/SIMD

#define NC   5                // hrrp Chebyshev: degree 4, 5x5 coeffs
#define NCG  5                // g0 Chebyshev: degree 4

__device__ __forceinline__ float fast_tanh(float x) {
    float e = __expf(2.0f * x);
    return 1.0f - __fdividef(2.0f, e + 1.0f);
}

__device__ __forceinline__ float sload(const float* p) {
    return __int_as_float(__builtin_amdgcn_readfirstlane(__float_as_int(*p)));
}

__device__ __forceinline__ float chebG(float v, const float (&CG)[NCG]) {
    float tt = 2.0f * v - 1.0f;
    float T2 = 2.0f * tt * tt - 1.0f;
    float T3 = 2.0f * tt * T2 - tt;
    float T4 = 2.0f * tt * T3 - T2;
    return CG[0] + CG[1] * tt + CG[2] * T2 + CG[3] * T3 + CG[4] * T4;
}

// ---------------- kT: build Chebyshev coefficients (unchanged, validated) ----
__global__ __launch_bounds__(128) void kT(
    const float* __restrict__ g0_w1, const float* __restrict__ g0_b1,
    const float* __restrict__ g0_w2, const float* __restrict__ g0_b2,
    const float* __restrict__ h_w1,  const float* __restrict__ h_b1,
    const float* __restrict__ h_w2,  const float* __restrict__ h_b2,
    float* __restrict__ CH, float* __restrict__ CG)
{
    __shared__ float cp[NC * NC];
    __shared__ float cg[NCG * NCG];
    __shared__ float F[NC * NC];
    __shared__ float Fg[NCG];
    int t = threadIdx.x;
    if (t < NC * NC) {
        int p = t / NC, i = t - NC * p;
        cp[t] = cosf((float)M_PI * (float)p * ((float)i + 0.5f) / (float)NC);
    } else if (t < NC * NC + NCG * NCG) {
        int u = t - NC * NC;
        int p = u / NCG, i = u - NCG * p;
        cg[u] = cosf((float)M_PI * (float)p * ((float)i + 0.5f) / (float)NCG);
    }
    __syncthreads();
    if (t < NC * NC) {
        int i = t / NC, j = t - NC * i;
        float x = 0.5f * (cp[NC + i] + 1.0f);
        float y = 0.5f * (cp[NC + j] + 1.0f);
        float s = 0.f;
        #pragma unroll
        for (int k = 0; k < NF; ++k) {
            float w0 = h_w1[k], w1 = h_w1[NF + k], bb = h_b1[k], w2 = h_w2[k];
            s += (fast_tanh(x * w0 + y * w1 + bb) + fast_tanh(y * w0 + x * w1 + bb)) * w2;
        }
        F[t] = 0.5f * s + h_b2[0];
    } else if (t < NC * NC + NCG) {
        int i = t - NC * NC;
        float x = 0.5f * (cg[NCG + i] + 1.0f);
        float g = g0_b2[0];
        #pragma unroll
        for (int k = 0; k < NF; ++k)
            g += fast_tanh(x * g0_w1[k] + g0_b1[k]) * g0_w2[k];
        Fg[i] = g;
    }
    __syncthreads();
    if (t < NC * NC) {
        int p = t / NC, q = t - NC * p;
        float sum = 0.f;
        #pragma unroll
        for (int i = 0; i < NC; ++i)
            #pragma unroll
            for (int j = 0; j < NC; ++j)
                sum += F[i * NC + j] * cp[p * NC + i] * cp[q * NC + j];
        float kp = p ? 1.0f : 0.5f, kq = q ? 1.0f : 0.5f;
        CH[t] = (4.0f / (float)(NC * NC)) * kp * kq * sum;
    } else if (t < NC * NC + NCG) {
        int p = t - NC * NC;
        float sum = 0.f;
        #pragma unroll
        for (int i = 0; i < NCG; ++i)
            sum += Fg[i] * cg[p * NCG + i];
        CG[p] = (2.0f / (float)NCG) * (p ? 1.0f : 0.5f) * sum;
    }
}

// ---------------- register-streaming helpers (validated in R8) ----------------
__device__ __forceinline__ void loadrow(const float* __restrict__ base, int y,
                                        int xb, float (&d)[8]) {
    const float* r = base + ((y & 511) << 9) + xb;
    float4 a = *(const float4*)r;
    float4 b = *(const float4*)(r + 4);
    d[0]=a.x; d[1]=a.y; d[2]=a.z; d[3]=a.w;
    d[4]=b.x; d[5]=b.y; d[6]=b.z; d[7]=b.w;
}

__device__ __forceinline__ void grow(const float (&v)[8], const float (&CG)[NCG],
                                     float (&g)[8]) {
    #pragma unroll
    for (int x = 0; x < 8; ++x) g[x] = chebG(v[x], CG);
}

// WU[x]=hrrp(a[x], up[x]); WL[x]=hrrp(a[x], a[x-1]) with x-wrap via lane shuffle
__device__ __forceinline__ void wrow(const float (&a)[8], const float (&up)[8],
                                     int lane, const float (&CH)[NC*NC],
                                     float (&WU)[8], float (&WL)[8]) {
    float lft = __shfl(a[7], (lane + 63) & 63, 64);
    #pragma unroll
    for (int x = 0; x < 8; ++x) {
        float ta = 2.f * a[x] - 1.f;
        float T2 = 2.f*ta*ta - 1.f;
        float T3 = 2.f*ta*T2 - ta;
        float T4 = 2.f*ta*T3 - T2;
        float s0 = CH[0] + CH[5]*ta + CH[10]*T2 + CH[15]*T3 + CH[20]*T4;
        float s1 = CH[1] + CH[6]*ta + CH[11]*T2 + CH[16]*T3 + CH[21]*T4;
        float s2 = CH[2] + CH[7]*ta + CH[12]*T2 + CH[17]*T3 + CH[22]*T4;
        float s3 = CH[3] + CH[8]*ta + CH[13]*T2 + CH[18]*T3 + CH[23]*T4;
        float s4 = CH[4] + CH[9]*ta + CH[14]*T2 + CH[19]*T3 + CH[24]*T4;
        float tu = 2.f*up[x] - 1.f;
        float U2 = 2.f*tu*tu - 1.f, U3 = 2.f*tu*U2 - tu, U4 = 2.f*tu*U3 - U2;
        WU[x] = s0 + s1*tu + s2*U2 + s3*U3 + s4*U4;
        float lv = x ? a[x-1] : lft;
        float tl = 2.f*lv - 1.f;
        float L2_ = 2.f*tl*tl - 1.f, L3_ = 2.f*tl*L2_ - tl, L4_ = 2.f*tl*L3_ - L2_;
        WL[x] = s0 + s1*tl + s2*L2_ + s3*L3_ + s4*L4_;
    }
}

__device__ __forceinline__ void errrow(const float (&c1r)[8], const float (&c0c)[8],
                                       const float (&Gup)[8], const float (&Gc)[8],
                                       const float (&Gdn)[8], int lane,
                                       float (&E)[8]) {
    float lf = __shfl(Gc[7], (lane + 63) & 63, 64);
    float rt = __shfl(Gc[0], (lane + 1) & 63, 64);
    #pragma unroll
    for (int x = 0; x < 8; ++x) {
        float gl = x ? Gc[x-1] : lf;
        float gr = (x < 7) ? Gc[x+1] : rt;
        float lap = Gup[x] + Gdn[x] + gl + gr - 4.f * Gc[x];
        E[x] = c1r[x] - c0c[x] - lap;
    }
}

__device__ __forceinline__ float lossrow(
    const float (&WUp)[8],  const float (&WLp)[8],
    const float (&WUp2)[8], const float (&WLp2)[8],
    const float (&WUc)[8],
    const float (&Ec)[8],   const float (&Ep)[8], int lane)
{
    int lm = (lane + 63) & 63, lp = (lane + 1) & 63;
    float wlp_r  = __shfl(WLp[0],  lp, 64);
    float wlp2_r = __shfl(WLp2[0], lp, 64);
    float wup_l  = __shfl(WUp[7],  lm, 64);
    float wlp_l  = __shfl(WLp[7],  lm, 64);
    float wuc_l  = __shfl(WUc[7],  lm, 64);
    float ec_l   = __shfl(Ec[7],   lm, 64);
    float acc = 0.f;
    #pragma unroll
    for (int x = 0; x < 8; ++x) {
        float wu = WUp[x], wl = WLp[x];
        float wlR  = (x < 7) ? WLp[x+1]  : wlp_r;
        float wl2R = (x < 7) ? WLp2[x+1] : wlp2_r;
        float wuL  = x ? WUp[x-1] : wup_l;
        float wlL  = x ? WLp[x-1] : wlp_l;
        float wucL = x ? WUc[x-1] : wuc_l;
        float eL   = x ? Ec[x-1]  : ec_l;
        float oii_p = wu + wl + WUc[x] + wlR;
        float oii_u = WUp2[x] + WLp2[x] + wu + wl2R;
        float oii_l = wuL + wlL + wucL + wl;
        float e = Ec[x], eu = Ep[x];
        float det0 = oii_p * oii_u - wu * wu;
        float l0 = det0 + __fdividef(e*e*oii_u + eu*eu*oii_p + 2.f*e*eu*wu, det0);
        float det1 = oii_p * oii_l - wl * wl;
        float l1 = det1 + __fdividef(e*e*oii_l + eL*eL*oii_p + 2.f*e*eL*wl, det1);
        acc += l0 + l1;
    }
    return acc;
}

// ---------------- kF: wave-autonomous, 2 waves/SIMD, prefetched ----------------
__global__ __launch_bounds__(TPB, 2) void kF(
    const float* __restrict__ c, const float* __restrict__ CHg,
    const float* __restrict__ CGg, float* __restrict__ partial)
{
    __shared__ float wsum[4];

    float CH[NC * NC], CG[NCG];
    #pragma unroll
    for (int i = 0; i < NC * NC; ++i) CH[i] = sload(CHg + i);
    #pragma unroll
    for (int i = 0; i < NCG; ++i)     CG[i] = sload(CGg + i);

    int tid  = threadIdx.x;
    int lane = tid & 63;
    // XCD chunked swizzle: round-robin bid -> XCD, so img == XCD id
    int sb   = ((blockIdx.x & 7) << 6) + (blockIdx.x >> 3);   // 0..511 bijective
    int wid  = (sb << 2) + (tid >> 6);      // 0..2047 strips
    int img  = wid >> 8;                    // 256 strips per image
    int Y0   = (wid & 255) << 1;            // RROWS=2
    const float* c0g = c + (size_t)img * 2 * HW;
    const float* c1g = c0g + HW;
    int xb = lane << 3;                     // 8 contiguous cols per lane

    // circular register buffers
    float c0s[2][8], Gs[3][8], WUs[3][8], WLs[3][8], Es[2][8];
    float nc0[2][8], nc1[2][8];             // prefetch double-buffers

    // ---- warmup: state for first step y = Y0+1, plus step-0 prefetch ----
    {
        float c0m2[8], c0m1[8], Gm2[8], c1t[8];
        loadrow(c0g, Y0 - 2, xb, c0m2);
        loadrow(c0g, Y0 - 1, xb, c0m1);
        loadrow(c0g, Y0,     xb, c0s[0]);
        loadrow(c1g, Y0 - 1, xb, c1t);
        loadrow(c0g, Y0 + 1, xb, nc0[0]);   // step 0's current c0 row
        loadrow(c1g, Y0,     xb, nc1[0]);   // step 0's c1 row
        grow(c0m2, CG, Gm2);
        grow(c0m1, CG, Gs[0]);              // G[Y0-1]
        grow(c0s[0], CG, Gs[1]);            // G[Y0]
        wrow(c0m1, c0m2, lane, CH, WUs[0], WLs[0]);   // W[Y0-1]
        wrow(c0s[0], c0m1, lane, CH, WUs[1], WLs[1]); // W[Y0]
        errrow(c1t, c0m1, Gm2, Gs[0], Gs[1], lane, Es[0]); // ERR[Y0-1]
    }

    float acc = 0.f;
    #pragma unroll
    for (int k = 0; k < RROWS; ++k) {
        int y = Y0 + 1 + k;
        const int icC = (k + 1) & 1, icP = k & 1;
        const int ig2 = k % 3, ig1 = (k + 1) % 3, igC = (k + 2) % 3;
        const int iw2 = k % 3, iw1 = (k + 1) % 3, iwC = (k + 2) % 3;
        const int ieP = k & 1, ieC = (k + 1) & 1;
        const int ipf = k & 1, ipn = (k + 1) & 1;

        // issue next step's loads first (they land during this step's compute)
        if (k + 1 < RROWS) {
            loadrow(c0g, y + 1, xb, nc0[ipn]);
            loadrow(c1g, y,     xb, nc1[ipn]);
        }
        // consume prefetched rows
        #pragma unroll
        for (int x = 0; x < 8; ++x) c0s[icC][x] = nc0[ipf][x];

        grow(c0s[icC], CG, Gs[igC]);
        wrow(c0s[icC], c0s[icP], lane, CH, WUs[iwC], WLs[iwC]);
        errrow(nc1[ipf], c0s[icP], Gs[ig2], Gs[ig1], Gs[igC], lane, Es[ieC]);
        acc += lossrow(WUs[iw1], WLs[iw1], WUs[iw2], WLs[iw2], WUs[iwC],
                       Es[ieC], Es[ieP], lane);
    }

    // ---- block reduce (deterministic) ----
    #pragma unroll
    for (int off = 32; off > 0; off >>= 1)
        acc += __shfl_down(acc, off, 64);
    if (lane == 0) wsum[tid >> 6] = acc;
    __syncthreads();
    if (tid == 0)
        partial[blockIdx.x] = wsum[0] + wsum[1] + wsum[2] + wsum[3];
}

// ---------------- kD: deterministic final reduction ----------------
__global__ __launch_bounds__(TPB) void kD(
    const float* __restrict__ partial, float* __restrict__ out)
{
    __shared__ double sm[TPB];
    double acc = 0.0;
    for (int i = threadIdx.x; i < NBLKF; i += TPB)
        acc += (double)partial[i];
    sm[threadIdx.x] = acc;
    __syncthreads();
    #pragma unroll
    for (int s = TPB / 2; s > 0; s >>= 1) {
        if (threadIdx.x < s) sm[threadIdx.x] += sm[threadIdx.x + s];
        __syncthreads();
    }
    if (threadIdx.x == 0)
        out[0] = (float)(0.5 * sm[0] / (double)NROWS);
}

extern "C" void kernel_launch(void* const* d_in, const int* in_sizes, int n_in,
                              void* d_out, int out_size, void* d_ws, size_t ws_size,
                              hipStream_t stream) {
    const float* c     = (const float*)d_in[0];
    const float* g0_w1 = (const float*)d_in[1];
    const float* g0_b1 = (const float*)d_in[2];
    const float* g0_w2 = (const float*)d_in[3];
    const float* g0_b2 = (const float*)d_in[4];
    const float* h_w1  = (const float*)d_in[5];
    const float* h_b1  = (const float*)d_in[6];
    const float* h_w2  = (const float*)d_in[7];
    const float* h_b2  = (const float*)d_in[8];
    float* out = (float*)d_out;

    // ws layout: CH | CG | partial
    float* ws = (float*)d_ws;
    float* CH = ws;
    float* CG = CH + NC * NC;
    float* PARTIAL = CG + NCG;

    kT<<<dim3(1), dim3(128), 0, stream>>>(
        g0_w1, g0_b1, g0_w2, g0_b2, h_w1, h_b1, h_w2, h_b2, CH, CG);
    kF<<<dim3(NBLKF), dim3(TPB), 0, stream>>>(c, CH, CG, PARTIAL);
    kD<<<1, dim3(TPB), 0, stream>>>(PARTIAL, out);
}

// Round 10
// 16.971 us; speedup vs baseline: 1.3370x; 1.3370x over previous
//
#include <hip/hip_runtime.h>
#include <math.h>

#define NF   32
#define HGT  512
#define WID  512
#define BAT  8
#define HW   (HGT*WID)        // 262144
#define NPIX (BAT*HW)         // 2097152
#define NROWS (2*NPIX)        // 4194304
#define TPB  256

#define RROWS 4               // rows per wave strip (R8 best config)
#define NBLKF 256             // 256 blocks x 4 waves = 1024 strips

#define NC   5                // hrrp Chebyshev: degree 4, 5x5 coeffs
#define NCG  5                // g0 Chebyshev: degree 4 (5 nodes, same cos table)

__device__ __forceinline__ float fast_tanh(float x) {
    float e = __expf(2.0f * x);
    return 1.0f - __fdividef(2.0f, e + 1.0f);
}

__device__ __forceinline__ float chebG(float v, const float (&CG)[NCG]) {
    float tt = 2.0f * v - 1.0f;
    float T2 = 2.0f * tt * tt - 1.0f;
    float T3 = 2.0f * tt * T2 - tt;
    float T4 = 2.0f * tt * T3 - T2;
    return CG[0] + CG[1] * tt + CG[2] * T2 + CG[3] * T3 + CG[4] * T4;
}

// ---------------- register-streaming helpers (validated R8) ----------------
__device__ __forceinline__ void loadrow(const float* __restrict__ base, int y,
                                        int xb, float (&d)[8]) {
    const float* r = base + ((y & 511) << 9) + xb;
    float4 a = *(const float4*)r;
    float4 b = *(const float4*)(r + 4);
    d[0]=a.x; d[1]=a.y; d[2]=a.z; d[3]=a.w;
    d[4]=b.x; d[5]=b.y; d[6]=b.z; d[7]=b.w;
}

__device__ __forceinline__ void grow(const float (&v)[8], const float (&CG)[NCG],
                                     float (&g)[8]) {
    #pragma unroll
    for (int x = 0; x < 8; ++x) g[x] = chebG(v[x], CG);
}

// WU[x]=hrrp(a[x], up[x]); WL[x]=hrrp(a[x], a[x-1]) with x-wrap via lane shuffle
__device__ __forceinline__ void wrow(const float (&a)[8], const float (&up)[8],
                                     int lane, const float (&CH)[NC*NC],
                                     float (&WU)[8], float (&WL)[8]) {
    float lft = __shfl(a[7], (lane + 63) & 63, 64);
    #pragma unroll
    for (int x = 0; x < 8; ++x) {
        float ta = 2.f * a[x] - 1.f;
        float T2 = 2.f*ta*ta - 1.f;
        float T3 = 2.f*ta*T2 - ta;
        float T4 = 2.f*ta*T3 - T2;
        float s0 = CH[0] + CH[5]*ta + CH[10]*T2 + CH[15]*T3 + CH[20]*T4;
        float s1 = CH[1] + CH[6]*ta + CH[11]*T2 + CH[16]*T3 + CH[21]*T4;
        float s2 = CH[2] + CH[7]*ta + CH[12]*T2 + CH[17]*T3 + CH[22]*T4;
        float s3 = CH[3] + CH[8]*ta + CH[13]*T2 + CH[18]*T3 + CH[23]*T4;
        float s4 = CH[4] + CH[9]*ta + CH[14]*T2 + CH[19]*T3 + CH[24]*T4;
        float tu = 2.f*up[x] - 1.f;
        float U2 = 2.f*tu*tu - 1.f, U3 = 2.f*tu*U2 - tu, U4 = 2.f*tu*U3 - U2;
        WU[x] = s0 + s1*tu + s2*U2 + s3*U3 + s4*U4;
        float lv = x ? a[x-1] : lft;
        float tl = 2.f*lv - 1.f;
        float L2_ = 2.f*tl*tl - 1.f, L3_ = 2.f*tl*L2_ - tl, L4_ = 2.f*tl*L3_ - L2_;
        WL[x] = s0 + s1*tl + s2*L2_ + s3*L3_ + s4*L4_;
    }
}

__device__ __forceinline__ void errrow(const float (&c1r)[8], const float (&c0c)[8],
                                       const float (&Gup)[8], const float (&Gc)[8],
                                       const float (&Gdn)[8], int lane,
                                       float (&E)[8]) {
    float lf = __shfl(Gc[7], (lane + 63) & 63, 64);
    float rt = __shfl(Gc[0], (lane + 1) & 63, 64);
    #pragma unroll
    for (int x = 0; x < 8; ++x) {
        float gl = x ? Gc[x-1] : lf;
        float gr = (x < 7) ? Gc[x+1] : rt;
        float lap = Gup[x] + Gdn[x] + gl + gr - 4.f * Gc[x];
        E[x] = c1r[x] - c0c[x] - lap;
    }
}

__device__ __forceinline__ float lossrow(
    const float (&WUp)[8],  const float (&WLp)[8],
    const float (&WUp2)[8], const float (&WLp2)[8],
    const float (&WUc)[8],
    const float (&Ec)[8],   const float (&Ep)[8], int lane)
{
    int lm = (lane + 63) & 63, lp = (lane + 1) & 63;
    float wlp_r  = __shfl(WLp[0],  lp, 64);
    float wlp2_r = __shfl(WLp2[0], lp, 64);
    float wup_l  = __shfl(WUp[7],  lm, 64);
    float wlp_l  = __shfl(WLp[7],  lm, 64);
    float wuc_l  = __shfl(WUc[7],  lm, 64);
    float ec_l   = __shfl(Ec[7],   lm, 64);
    float acc = 0.f;
    #pragma unroll
    for (int x = 0; x < 8; ++x) {
        float wu = WUp[x], wl = WLp[x];
        float wlR  = (x < 7) ? WLp[x+1]  : wlp_r;
        float wl2R = (x < 7) ? WLp2[x+1] : wlp2_r;
        float wuL  = x ? WUp[x-1] : wup_l;
        float wlL  = x ? WLp[x-1] : wlp_l;
        float wucL = x ? WUc[x-1] : wuc_l;
        float eL   = x ? Ec[x-1]  : ec_l;
        float oii_p = wu + wl + WUc[x] + wlR;
        float oii_u = WUp2[x] + WLp2[x] + wu + wl2R;
        float oii_l = wuL + wlL + wucL + wl;
        float e = Ec[x], eu = Ep[x];
        float det0 = oii_p * oii_u - wu * wu;
        float l0 = det0 + __fdividef(e*e*oii_u + eu*eu*oii_p + 2.f*e*eu*wu, det0);
        float det1 = oii_p * oii_l - wl * wl;
        float l1 = det1 + __fdividef(e*e*oii_l + eL*eL*oii_p + 2.f*e*eL*wl, det1);
        acc += l0 + l1;
    }
    return acc;
}

// ---------------- kF: in-block coeffs + wave-autonomous streaming ----------
__global__ __launch_bounds__(TPB, 1) void kF(
    const float* __restrict__ c,
    const float* __restrict__ g0_w1, const float* __restrict__ g0_b1,
    const float* __restrict__ g0_w2, const float* __restrict__ g0_b2,
    const float* __restrict__ h_w1,  const float* __restrict__ h_b1,
    const float* __restrict__ h_w2,  const float* __restrict__ h_b2,
    float* __restrict__ partial)
{
    __shared__ float cp[NC * NC];      // cos(p*pi*(i+0.5)/5), shared by CH & CG
    __shared__ float Facc[NC * NC][8];
    __shared__ float Fgacc[NCG][8];
    __shared__ float F[NC * NC];
    __shared__ float Fg[NCG];
    __shared__ float CHs[NC * NC];
    __shared__ float CGs[NCG];
    __shared__ float wsum[4];

    int tid  = threadIdx.x;
    int lane = tid & 63;

    // ---- phase 0: cos table ----
    if (tid < NC * NC) {
        int p = tid / NC, i = tid - NC * p;
        cp[tid] = cosf((float)M_PI * (float)p * ((float)i + 0.5f) / (float)NC);
    }
    __syncthreads();

    // ---- phase 1: MLP evals at Chebyshev nodes (deterministic partials) ----
    if (tid < 200) {                       // 25 nodes x 8 parts, 4 k-terms each
        int n = tid >> 3, part = tid & 7;
        int ni = n / NC, nj = n - NC * ni;
        float x = 0.5f * (cp[NC + ni] + 1.0f);
        float y = 0.5f * (cp[NC + nj] + 1.0f);
        float s = 0.f;
        #pragma unroll
        for (int kk = 0; kk < 4; ++kk) {
            int k = part * 4 + kk;
            float w0 = h_w1[k], w1 = h_w1[NF + k], bb = h_b1[k], w2 = h_w2[k];
            s += (fast_tanh(x * w0 + y * w1 + bb) + fast_tanh(y * w0 + x * w1 + bb)) * w2;
        }
        Facc[n][part] = s;
    } else if (tid < 240) {                // 5 nodes x 8 parts
        int t2 = tid - 200;
        int n = t2 >> 3, part = t2 & 7;
        float x = 0.5f * (cp[NC + n] + 1.0f);
        float g = 0.f;
        #pragma unroll
        for (int kk = 0; kk < 4; ++kk) {
            int k = part * 4 + kk;
            g += fast_tanh(x * g0_w1[k] + g0_b1[k]) * g0_w2[k];
        }
        Fgacc[n][part] = g;
    }
    __syncthreads();

    // ---- phase 2: gather node values (fixed order) ----
    if (tid < NC * NC) {
        float s = 0.f;
        #pragma unroll
        for (int j = 0; j < 8; ++j) s += Facc[tid][j];
        F[tid] = 0.5f * s + h_b2[0];
    } else if (tid < NC * NC + NCG) {
        int n = tid - NC * NC;
        float s = 0.f;
        #pragma unroll
        for (int j = 0; j < 8; ++j) s += Fgacc[n][j];
        Fg[n] = s + g0_b2[0];
    }
    __syncthreads();

    // ---- phase 3: DCT -> coefficients ----
    if (tid < NC * NC) {
        int p = tid / NC, q = tid - NC * p;
        float sum = 0.f;
        #pragma unroll
        for (int i = 0; i < NC; ++i)
            #pragma unroll
            for (int j = 0; j < NC; ++j)
                sum += F[i * NC + j] * cp[p * NC + i] * cp[q * NC + j];
        float kp = p ? 1.0f : 0.5f, kq = q ? 1.0f : 0.5f;
        CHs[tid] = (4.0f / (float)(NC * NC)) * kp * kq * sum;
    } else if (tid < NC * NC + NCG) {
        int p = tid - NC * NC;
        float sum = 0.f;
        #pragma unroll
        for (int i = 0; i < NCG; ++i)
            sum += Fg[i] * cp[p * NC + i];
        CGs[p] = (2.0f / (float)NCG) * (p ? 1.0f : 0.5f) * sum;
    }
    __syncthreads();

    // ---- pin coefficients to SGPRs (LDS broadcast -> readfirstlane) ----
    float CH[NC * NC], CG[NCG];
    #pragma unroll
    for (int i = 0; i < NC * NC; ++i)
        CH[i] = __int_as_float(__builtin_amdgcn_readfirstlane(__float_as_int(CHs[i])));
    #pragma unroll
    for (int i = 0; i < NCG; ++i)
        CG[i] = __int_as_float(__builtin_amdgcn_readfirstlane(__float_as_int(CGs[i])));

    // ---- main: R8's wave-autonomous register streaming ----
    // XCD chunked swizzle (256 % 8 == 0 -> bijective)
    int sb   = ((blockIdx.x & 7) << 5) + (blockIdx.x >> 3);
    int wid  = (sb << 2) + (tid >> 6);      // 0..1023 strips
    int img  = wid >> 7;
    int Y0   = (wid & 127) << 2;            // RROWS=4
    const float* c0g = c + (size_t)img * 2 * HW;
    const float* c1g = c0g + HW;
    int xb = lane << 3;                     // 8 contiguous cols per lane

    float c0s[2][8], Gs[3][8], WUs[3][8], WLs[3][8], Es[2][8];

    {
        float c0m2[8], c0m1[8], Gm2[8], c1t[8];
        loadrow(c0g, Y0 - 2, xb, c0m2);
        loadrow(c0g, Y0 - 1, xb, c0m1);
        loadrow(c0g, Y0,     xb, c0s[0]);
        loadrow(c1g, Y0 - 1, xb, c1t);
        grow(c0m2, CG, Gm2);
        grow(c0m1, CG, Gs[0]);
        grow(c0s[0], CG, Gs[1]);
        wrow(c0m1, c0m2, lane, CH, WUs[0], WLs[0]);
        wrow(c0s[0], c0m1, lane, CH, WUs[1], WLs[1]);
        errrow(c1t, c0m1, Gm2, Gs[0], Gs[1], lane, Es[0]);
    }

    float acc = 0.f;
    #pragma unroll
    for (int k = 0; k < RROWS; ++k) {
        int y = Y0 + 1 + k;
        const int icC = (k + 1) & 1, icP = k & 1;
        const int ig2 = k % 3, ig1 = (k + 1) % 3, igC = (k + 2) % 3;
        const int iw2 = k % 3, iw1 = (k + 1) % 3, iwC = (k + 2) % 3;
        const int ieP = k & 1, ieC = (k + 1) & 1;
        float c1r[8];
        loadrow(c0g, y,     xb, c0s[icC]);
        loadrow(c1g, y - 1, xb, c1r);
        grow(c0s[icC], CG, Gs[igC]);
        wrow(c0s[icC], c0s[icP], lane, CH, WUs[iwC], WLs[iwC]);
        errrow(c1r, c0s[icP], Gs[ig2], Gs[ig1], Gs[igC], lane, Es[ieC]);
        acc += lossrow(WUs[iw1], WLs[iw1], WUs[iw2], WLs[iw2], WUs[iwC],
                       Es[ieC], Es[ieP], lane);
    }

    // ---- block reduce (deterministic) ----
    #pragma unroll
    for (int off = 32; off > 0; off >>= 1)
        acc += __shfl_down(acc, off, 64);
    if (lane == 0) wsum[tid >> 6] = acc;
    __syncthreads();
    if (tid == 0)
        partial[blockIdx.x] = wsum[0] + wsum[1] + wsum[2] + wsum[3];
}

// ---------------- kD: deterministic final reduction ----------------
__global__ __launch_bounds__(TPB) void kD(
    const float* __restrict__ partial, float* __restrict__ out)
{
    __shared__ double sm[TPB];
    double acc = 0.0;
    for (int i = threadIdx.x; i < NBLKF; i += TPB)
        acc += (double)partial[i];
    sm[threadIdx.x] = acc;
    __syncthreads();
    #pragma unroll
    for (int s = TPB / 2; s > 0; s >>= 1) {
        if (threadIdx.x < s) sm[threadIdx.x] += sm[threadIdx.x + s];
        __syncthreads();
    }
    if (threadIdx.x == 0)
        out[0] = (float)(0.5 * sm[0] / (double)NROWS);
}

extern "C" void kernel_launch(void* const* d_in, const int* in_sizes, int n_in,
                              void* d_out, int out_size, void* d_ws, size_t ws_size,
                              hipStream_t stream) {
    const float* c     = (const float*)d_in[0];
    const float* g0_w1 = (const float*)d_in[1];
    const float* g0_b1 = (const float*)d_in[2];
    const float* g0_w2 = (const float*)d_in[3];
    const float* g0_b2 = (const float*)d_in[4];
    const float* h_w1  = (const float*)d_in[5];
    const float* h_b1  = (const float*)d_in[6];
    const float* h_w2  = (const float*)d_in[7];
    const float* h_b2  = (const float*)d_in[8];
    float* out = (float*)d_out;

    float* PARTIAL = (float*)d_ws;

    kF<<<dim3(NBLKF), dim3(TPB), 0, stream>>>(
        c, g0_w1, g0_b1, g0_w2, g0_b2, h_w1, h_b1, h_w2, h_b2, PARTIAL);
    kD<<<1, dim3(TPB), 0, stream>>>(PARTIAL, out);
}

// Round 11
// 15.731 us; speedup vs baseline: 1.4423x; 1.0788x over previous
//
#include <hip/hip_runtime.h>
#include <math.h>

#define NF   32
#define HGT  512
#define WID  512
#define BAT  8
#define HW   (HGT*WID)        // 262144
#define NPIX (BAT*HW)         // 2097152
#define NROWS (2*NPIX)        // 4194304
#define TPB  256

#define RROWS 4               // rows per wave strip (R8/R10 best config)
#define NBLKF 256             // 256 blocks x 4 waves = 1024 strips

#define NC   4                // hrrp Chebyshev: degree 3, 4x4 coeffs
#define NCG  4                // g0 Chebyshev: degree 3

__device__ __forceinline__ float fast_tanh(float x) {
    float e = __expf(2.0f * x);
    return 1.0f - __fdividef(2.0f, e + 1.0f);
}

// ---------------- register-window helpers (no cross-lane shuffles) ----------
// window index j in [0,12) <-> column (xb-2+j) & 511
__device__ __forceinline__ void loadrow12(const float* __restrict__ base, int y,
                                          int xb, float (&d)[12]) {
    const float* r = base + ((y & 511) << 9);
    float2 p0 = *(const float2*)(r + ((xb - 2) & 511));
    float4 p1 = *(const float4*)(r + xb);
    float4 p2 = *(const float4*)(r + xb + 4);
    float2 p3 = *(const float2*)(r + ((xb + 8) & 511));
    d[0]=p0.x; d[1]=p0.y;
    d[2]=p1.x; d[3]=p1.y; d[4]=p1.z; d[5]=p1.w;
    d[6]=p2.x; d[7]=p2.y; d[8]=p2.z; d[9]=p2.w;
    d[10]=p3.x; d[11]=p3.y;
}

// G-only row: G[j] for j=0..10 (cols xb-2 .. xb+8)
__device__ __forceinline__ void growin(const float (&a)[12], const float (&CG)[NCG],
                                       float (&G)[11]) {
    #pragma unroll
    for (int j = 0; j <= 10; ++j) {
        float t = 2.f * a[j] - 1.f;
        float T2 = 2.f * t * t - 1.f;
        float T3 = 2.f * t * T2 - t;
        G[j] = CG[0] + CG[1] * t + CG[2] * T2 + CG[3] * T3;
    }
}

// Fused W+G row: G[0..10], WU/WL[0..9] (W idx k <-> col xb-1+k)
// WU[k]=hrrp(a,up), WL[k]=hrrp(a,left) with left's T basis loop-carried.
__device__ __forceinline__ void wgrow(const float (&a)[12], const float (&up)[12],
                                      const float (&CH)[NC*NC], const float (&CG)[NCG],
                                      float (&G)[11], float (&WU)[10], float (&WL)[10]) {
    float pt1 = 2.f * a[0] - 1.f;
    float pt2 = 2.f * pt1 * pt1 - 1.f;
    float pt3 = 2.f * pt1 * pt2 - pt1;
    G[0] = CG[0] + CG[1] * pt1 + CG[2] * pt2 + CG[3] * pt3;
    #pragma unroll
    for (int j = 1; j <= 10; ++j) {
        float tb = 2.f * a[j] - 1.f;
        float B2 = 2.f * tb * tb - 1.f;
        float B3 = 2.f * tb * B2 - tb;
        float s0 = CH[0] + CH[4] * tb + CH[8]  * B2 + CH[12] * B3;
        float s1 = CH[1] + CH[5] * tb + CH[9]  * B2 + CH[13] * B3;
        float s2 = CH[2] + CH[6] * tb + CH[10] * B2 + CH[14] * B3;
        float s3 = CH[3] + CH[7] * tb + CH[11] * B2 + CH[15] * B3;
        G[j] = CG[0] + CG[1] * tb + CG[2] * B2 + CG[3] * B3;
        float tu = 2.f * up[j] - 1.f;
        float U2 = 2.f * tu * tu - 1.f;
        float U3 = 2.f * tu * U2 - tu;
        WU[j - 1] = s0 + s1 * tu + s2 * U2 + s3 * U3;
        WL[j - 1] = s0 + s1 * pt1 + s2 * pt2 + s3 * pt3;
        pt1 = tb; pt2 = B2; pt3 = B3;
    }
}

// ERR row: E[0..8] (col xb-1+k... E idx k <-> col xb-1+k? mapping: E[k] <-> window j=k+1)
__device__ __forceinline__ void errrow(const float (&c1r)[12], const float (&c0c)[12],
                                       const float (&Gup)[11], const float (&Gc)[11],
                                       const float (&Gdn)[11], float (&E)[9]) {
    #pragma unroll
    for (int j = 1; j <= 9; ++j) {
        float lap = Gup[j] + Gdn[j] + Gc[j - 1] + Gc[j + 1] - 4.f * Gc[j];
        E[j - 1] = c1r[j] - c0c[j] - lap;
    }
}

// loss over cols xb..xb+7 (window j=2..9). W idx wj=j-1, E idx ej=j-1.
__device__ __forceinline__ float lossrow(
    const float (&WUp)[10],  const float (&WLp)[10],
    const float (&WUp2)[10], const float (&WLp2)[10],
    const float (&WUc)[10],
    const float (&Ec)[9],    const float (&Ep)[9])
{
    float acc = 0.f;
    #pragma unroll
    for (int j = 2; j <= 9; ++j) {
        const int wj = j - 1, ej = j - 1;
        float wu = WUp[wj], wl = WLp[wj];
        float oii_p = wu + wl + WUc[wj] + WLp[wj + 1];
        float oii_u = WUp2[wj] + WLp2[wj] + wu + WLp2[wj + 1];
        float oii_l = WUp[wj - 1] + WLp[wj - 1] + WUc[wj - 1] + wl;
        float e = Ec[ej], eu = Ep[ej], eL = Ec[ej - 1];
        float det0 = oii_p * oii_u - wu * wu;
        float l0 = det0 + __fdividef(e*e*oii_u + eu*eu*oii_p + 2.f*e*eu*wu, det0);
        float det1 = oii_p * oii_l - wl * wl;
        float l1 = det1 + __fdividef(e*e*oii_l + eL*eL*oii_p + 2.f*e*eL*wl, det1);
        acc += l0 + l1;
    }
    return acc;
}

// ---------------- kF: in-block coeffs + shuffle-free register streaming ----
__global__ __launch_bounds__(TPB, 1) void kF(
    const float* __restrict__ c,
    const float* __restrict__ g0_w1, const float* __restrict__ g0_b1,
    const float* __restrict__ g0_w2, const float* __restrict__ g0_b2,
    const float* __restrict__ h_w1,  const float* __restrict__ h_b1,
    const float* __restrict__ h_w2,  const float* __restrict__ h_b2,
    float* __restrict__ partial)
{
    __shared__ float cp[NC * NC];      // cos(p*pi*(i+0.5)/4), shared by CH & CG
    __shared__ float Facc[NC * NC][8];
    __shared__ float Fgacc[NCG][8];
    __shared__ float F[NC * NC];
    __shared__ float Fg[NCG];
    __shared__ float CHs[NC * NC];
    __shared__ float CGs[NCG];
    __shared__ float wsum[4];

    int tid  = threadIdx.x;
    int lane = tid & 63;

    // ---- phase 0: cos table ----
    if (tid < NC * NC) {
        int p = tid >> 2, i = tid & 3;
        cp[tid] = cosf((float)M_PI * (float)p * ((float)i + 0.5f) / (float)NC);
    }
    __syncthreads();

    // ---- phase 1: MLP evals at Chebyshev nodes (deterministic partials) ----
    if (tid < 128) {                       // 16 nodes x 8 parts, 4 k-terms each
        int n = tid >> 3, part = tid & 7;
        int ni = n >> 2, nj = n & 3;
        float x = 0.5f * (cp[NC + ni] + 1.0f);
        float y = 0.5f * (cp[NC + nj] + 1.0f);
        float s = 0.f;
        #pragma unroll
        for (int kk = 0; kk < 4; ++kk) {
            int k = part * 4 + kk;
            float w0 = h_w1[k], w1 = h_w1[NF + k], bb = h_b1[k], w2 = h_w2[k];
            s += (fast_tanh(x * w0 + y * w1 + bb) + fast_tanh(y * w0 + x * w1 + bb)) * w2;
        }
        Facc[n][part] = s;
    } else if (tid < 160) {                // 4 nodes x 8 parts
        int t2 = tid - 128;
        int n = t2 >> 3, part = t2 & 7;
        float x = 0.5f * (cp[NC + n] + 1.0f);
        float g = 0.f;
        #pragma unroll
        for (int kk = 0; kk < 4; ++kk) {
            int k = part * 4 + kk;
            g += fast_tanh(x * g0_w1[k] + g0_b1[k]) * g0_w2[k];
        }
        Fgacc[n][part] = g;
    }
    __syncthreads();

    // ---- phase 2: gather node values (fixed order) ----
    if (tid < NC * NC) {
        float s = 0.f;
        #pragma unroll
        for (int j = 0; j < 8; ++j) s += Facc[tid][j];
        F[tid] = 0.5f * s + h_b2[0];
    } else if (tid < NC * NC + NCG) {
        int n = tid - NC * NC;
        float s = 0.f;
        #pragma unroll
        for (int j = 0; j < 8; ++j) s += Fgacc[n][j];
        Fg[n] = s + g0_b2[0];
    }
    __syncthreads();

    // ---- phase 3: DCT -> coefficients ----
    if (tid < NC * NC) {
        int p = tid >> 2, q = tid & 3;
        float sum = 0.f;
        #pragma unroll
        for (int i = 0; i < NC; ++i)
            #pragma unroll
            for (int j = 0; j < NC; ++j)
                sum += F[i * NC + j] * cp[p * NC + i] * cp[q * NC + j];
        float kp = p ? 1.0f : 0.5f, kq = q ? 1.0f : 0.5f;
        CHs[tid] = (4.0f / (float)(NC * NC)) * kp * kq * sum;
    } else if (tid < NC * NC + NCG) {
        int p = tid - NC * NC;
        float sum = 0.f;
        #pragma unroll
        for (int i = 0; i < NCG; ++i)
            sum += Fg[i] * cp[p * NC + i];
        CGs[p] = (2.0f / (float)NCG) * (p ? 1.0f : 0.5f) * sum;
    }
    __syncthreads();

    // ---- pin coefficients to SGPRs (LDS broadcast -> readfirstlane) ----
    float CH[NC * NC], CG[NCG];
    #pragma unroll
    for (int i = 0; i < NC * NC; ++i)
        CH[i] = __int_as_float(__builtin_amdgcn_readfirstlane(__float_as_int(CHs[i])));
    #pragma unroll
    for (int i = 0; i < NCG; ++i)
        CG[i] = __int_as_float(__builtin_amdgcn_readfirstlane(__float_as_int(CGs[i])));

    // ---- main: wave-autonomous register streaming, 12-col windows ----
    // XCD chunked swizzle (256 % 8 == 0 -> bijective)
    int sb   = ((blockIdx.x & 7) << 5) + (blockIdx.x >> 3);
    int wid  = (sb << 2) + (tid >> 6);      // 0..1023 strips
    int img  = wid >> 7;
    int Y0   = (wid & 127) << 2;            // RROWS=4
    const float* c0g = c + (size_t)img * 2 * HW;
    const float* c1g = c0g + HW;
    int xb = lane << 3;                     // 8 interior cols per lane

    float c0s[2][12], Gs[3][11], WUs[3][10], WLs[3][10], Es[2][9];

    {
        float c0m2[12], c0m1[12], Gm2[11], c1t[12];
        loadrow12(c0g, Y0 - 2, xb, c0m2);
        loadrow12(c0g, Y0 - 1, xb, c0m1);
        loadrow12(c0g, Y0,     xb, c0s[0]);
        loadrow12(c1g, Y0 - 1, xb, c1t);
        growin(c0m2, CG, Gm2);
        wgrow(c0m1, c0m2, CH, CG, Gs[0], WUs[0], WLs[0]);   // W,G row Y0-1
        wgrow(c0s[0], c0m1, CH, CG, Gs[1], WUs[1], WLs[1]); // W,G row Y0
        errrow(c1t, c0m1, Gm2, Gs[0], Gs[1], Es[0]);        // ERR row Y0-1
    }

    float acc = 0.f;
    #pragma unroll
    for (int k = 0; k < RROWS; ++k) {
        int y = Y0 + 1 + k;
        const int icC = (k + 1) & 1, icP = k & 1;
        const int ig2 = k % 3, ig1 = (k + 1) % 3, igC = (k + 2) % 3;
        const int iw2 = k % 3, iw1 = (k + 1) % 3, iwC = (k + 2) % 3;
        const int ieP = k & 1, ieC = (k + 1) & 1;
        float c1r[12];
        loadrow12(c0g, y,     xb, c0s[icC]);
        loadrow12(c1g, y - 1, xb, c1r);
        wgrow(c0s[icC], c0s[icP], CH, CG, Gs[igC], WUs[iwC], WLs[iwC]);
        errrow(c1r, c0s[icP], Gs[ig2], Gs[ig1], Gs[igC], Es[ieC]);
        acc += lossrow(WUs[iw1], WLs[iw1], WUs[iw2], WLs[iw2], WUs[iwC],
                       Es[ieC], Es[ieP]);
    }

    // ---- block reduce (deterministic) ----
    #pragma unroll
    for (int off = 32; off > 0; off >>= 1)
        acc += __shfl_down(acc, off, 64);
    if (lane == 0) wsum[tid >> 6] = acc;
    __syncthreads();
    if (tid == 0)
        partial[blockIdx.x] = wsum[0] + wsum[1] + wsum[2] + wsum[3];
}

// ---------------- kD: deterministic final reduction ----------------
__global__ __launch_bounds__(TPB) void kD(
    const float* __restrict__ partial, float* __restrict__ out)
{
    __shared__ double sm[TPB];
    double acc = 0.0;
    for (int i = threadIdx.x; i < NBLKF; i += TPB)
        acc += (double)partial[i];
    sm[threadIdx.x] = acc;
    __syncthreads();
    #pragma unroll
    for (int s = TPB / 2; s > 0; s >>= 1) {
        if (threadIdx.x < s) sm[threadIdx.x] += sm[threadIdx.x + s];
        __syncthreads();
    }
    if (threadIdx.x == 0)
        out[0] = (float)(0.5 * sm[0] / (double)NROWS);
}

extern "C" void kernel_launch(void* const* d_in, const int* in_sizes, int n_in,
                              void* d_out, int out_size, void* d_ws, size_t ws_size,
                              hipStream_t stream) {
    const float* c     = (const float*)d_in[0];
    const float* g0_w1 = (const float*)d_in[1];
    const float* g0_b1 = (const float*)d_in[2];
    const float* g0_w2 = (const float*)d_in[3];
    const float* g0_b2 = (const float*)d_in[4];
    const float* h_w1  = (const float*)d_in[5];
    const float* h_b1  = (const float*)d_in[6];
    const float* h_w2  = (const float*)d_in[7];
    const float* h_b2  = (const float*)d_in[8];
    float* out = (float*)d_out;

    float* PARTIAL = (float*)d_ws;

    kF<<<dim3(NBLKF), dim3(TPB), 0, stream>>>(
        c, g0_w1, g0_b1, g0_w2, g0_b2, h_w1, h_b1, h_w2, h_b2, PARTIAL);
    kD<<<1, dim3(TPB), 0, stream>>>(PARTIAL, out);
}